// Round 6
// baseline (143.967 us; speedup 1.0000x reference)
//
#include <hip/hip_runtime.h>
#include <stdint.h>

typedef __attribute__((ext_vector_type(8))) short short8;
typedef __attribute__((ext_vector_type(4))) float f32x4;
typedef __attribute__((ext_vector_type(4))) unsigned int u32x4;
typedef __attribute__((ext_vector_type(4))) unsigned short u16x4;

// B=8, S=2048, D=1024, H=64
// ws: Wb2 bf16 fragment-ordered [12 mtile][16 kchunk][2 ks][64 lane][8] @0 (384 KB)
//     Qw bf16 [16384][64] @393216 ; Kw @2490368 ; Vtw [512][2048] @4587520 ;
//     Op fp32 [4][16384][64] @6684672 (16 MB) ; lp fp32 [4][16384] @23461888

__device__ __forceinline__ unsigned short f2bf(float f){
  unsigned int u = __builtin_bit_cast(unsigned int, f);
  u = u + 0x7fffu + ((u >> 16) & 1u);
  return (unsigned short)(u >> 16);
}

// ---------------- kernel 0: W -> bf16 pack in MFMA-fragment order.
// A-frag (mt, kc, ks): lane qd*16+ln holds row h=mt*16+ln, cols kc*64+ks*32+qd*8..+7
__global__ __launch_bounds__(256) void wcvt_k(const float* __restrict__ Wk,
                                              const float* __restrict__ Wq,
                                              const float* __restrict__ Wv,
                                              unsigned short* __restrict__ Wb2){
  int t = blockIdx.x * 256 + threadIdx.x;
  int e = t * 8;
  int row = e >> 10, col = e & 1023;
  const float* src = (row < 64)  ? (Wq + row * 1024 + col)
                   : (row < 128) ? (Wk + (row - 64) * 1024 + col)
                   :               (Wv + (row - 128) * 1024 + col);
  f32x4 a = *(const f32x4*)src;
  f32x4 b = *(const f32x4*)(src + 4);
  u16x4 lo = { f2bf(a.x), f2bf(a.y), f2bf(a.z), f2bf(a.w) };
  u16x4 hi = { f2bf(b.x), f2bf(b.y), f2bf(b.z), f2bf(b.w) };
  const int mtile = row >> 4, lnn = row & 15;
  const int kchunk = col >> 6, ks = (col >> 5) & 1, qd = (col >> 3) & 3;
  const int lane = qd * 16 + lnn;
  const int off = ((((mtile * 16 + kchunk) * 2 + ks) * 64 + lane)) * 8;
  *(u16x4*)(Wb2 + off)     = lo;
  *(u16x4*)(Wb2 + off + 4) = hi;
}

// ---------------- kernel 1: QKV GEMM — BARRIER-FREE. grid 1024 x 192 thr (3 waves).
// Wave w: m-tiles [4w,4w+4) (w=0:Q, 1:K, 2:V) x 16 s-rows. X staged in wave-PRIVATE
// double-buffered LDS (no __syncthreads anywhere -> no vmcnt(0) drains; compiler
// pipelines with fine-grained waitcnt). W frags register-dbuf, coalesced 1KB loads.
__global__ __launch_bounds__(192, 3) void qkv_k(const float* __restrict__ X,
                                                const unsigned short* __restrict__ Wb2,
                                                unsigned short* __restrict__ Qw,
                                                unsigned short* __restrict__ Kw,
                                                unsigned short* __restrict__ Vtw){
  __shared__ unsigned short Xb[3][2][16][72];   // per-wave private dbuf, 13.8 KB
  const int t = threadIdx.x, w = t >> 6, l = t & 63, qd = l >> 4, ln = l & 15;
  const int s0 = blockIdx.x * 16, b = s0 >> 11, sb = s0 & 2047;
  const int mset = w * 4;
  const int xrow = l >> 4, xcol = (l & 15) * 4;  // lane (i): row i*4+xrow, col xcol

  f32x4 acc[4];
#pragma unroll
  for (int i = 0; i < 4; ++i) acc[i] = (f32x4){0.f, 0.f, 0.f, 0.f};

  short8 wreg[2][4][2];
  f32x4 xr[4];
  // prologue: W frags + X chunk for kk=0
#pragma unroll
  for (int i = 0; i < 4; ++i)
#pragma unroll
    for (int ks = 0; ks < 2; ++ks)
      wreg[0][i][ks] = *(const short8*)(Wb2 + ((((mset + i) * 16 + 0) * 2 + ks) * 64 + l) * 8);
#pragma unroll
  for (int i = 0; i < 4; ++i)
    xr[i] = *(const f32x4*)(X + (s0 + i * 4 + xrow) * 1024 + xcol);
#pragma unroll
  for (int i = 0; i < 4; ++i){
    u16x4 pk = { f2bf(xr[i].x), f2bf(xr[i].y), f2bf(xr[i].z), f2bf(xr[i].w) };
    *(u16x4*)&Xb[w][0][i * 4 + xrow][xcol] = pk;
  }

  for (int kk = 0; kk < 16; ++kk){
    const int cur = kk & 1, nxt = cur ^ 1;
    if (kk < 15){
      const int k0 = (kk + 1) * 64;
#pragma unroll
      for (int i = 0; i < 4; ++i)
        xr[i] = *(const f32x4*)(X + (s0 + i * 4 + xrow) * 1024 + k0 + xcol);
#pragma unroll
      for (int i = 0; i < 4; ++i)
#pragma unroll
        for (int ks = 0; ks < 2; ++ks)
          wreg[nxt][i][ks] = *(const short8*)(Wb2 + ((((mset + i) * 16 + kk + 1) * 2 + ks) * 64 + l) * 8);
    }
#pragma unroll
    for (int ks = 0; ks < 2; ++ks){
      short8 bfr = *(const short8*)&Xb[w][cur][ln][ks * 32 + qd * 8];
#pragma unroll
      for (int i = 0; i < 4; ++i)
        acc[i] = __builtin_amdgcn_mfma_f32_16x16x32_bf16(wreg[cur][i][ks], bfr, acc[i], 0, 0, 0);
    }
    if (kk < 15){
#pragma unroll
      for (int i = 0; i < 4; ++i){
        u16x4 pk = { f2bf(xr[i].x), f2bf(xr[i].y), f2bf(xr[i].z), f2bf(xr[i].w) };
        *(u16x4*)&Xb[w][nxt][i * 4 + xrow][xcol] = pk;
      }
    }
  }
  // epilogue: D reg r -> h = (mset+i)*16 + qd*4 + r, col s = sb + ln
  const int s = sb + ln;
#pragma unroll
  for (int i = 0; i < 4; ++i){
    const int h0 = (mset + i) * 16 + qd * 4;
    f32x4 v = acc[i];
    u16x4 pk = { f2bf(v.x), f2bf(v.y), f2bf(v.z), f2bf(v.w) };
    if (h0 < 64){
      *(u16x4*)(Qw + (b * 2048 + s) * 64 + h0) = pk;
    } else if (h0 < 128){
      *(u16x4*)(Kw + (b * 2048 + s) * 64 + (h0 - 64)) = pk;
    } else {
      const int hh = h0 - 128;
      Vtw[(b * 64 + hh + 0) * 2048 + s] = pk.x;
      Vtw[(b * 64 + hh + 1) * 2048 + s] = pk.y;
      Vtw[(b * 64 + hh + 2) * 2048 + s] = pk.z;
      Vtw[(b * 64 + hh + 3) * 2048 + s] = pk.w;
    }
  }
}

// ---------------- kernel 2: causal attention, kv-chunked (8 j-steps/chunk).
// grid 640 = 8 batch x 80 (qi,c) pairs, longest qi first. Private per-chunk
// partial buffers (no atomics/memsets). 4 waves x 16 q-rows, P wave-private,
// double-buffered K/V, 1 barrier/j-step, no-max softmax (bounded scores).
__global__ __launch_bounds__(256) void attn_k(const unsigned short* __restrict__ Qw,
                                              const unsigned short* __restrict__ Kw,
                                              const unsigned short* __restrict__ Vtw,
                                              float* __restrict__ Op,
                                              float* __restrict__ lp){
  __shared__ unsigned short Kl[2][64][72];
  __shared__ unsigned short Vl[2][64][72];
  __shared__ unsigned short Pl[4][16][72];
  const int t = threadIdx.x, w = t >> 6, l = t & 63, qd = l >> 4, ln = l & 15;
  const int b = blockIdx.x & 7;
  const int sp = blockIdx.x >> 3;
  int qi, c;
  if (sp < 32){ qi = 31 - (sp >> 2); c = sp & 3; }
  else if (sp < 56){ int u = sp - 32; int d = u / 3; qi = 23 - d; c = u - d * 3; }
  else if (sp < 72){ int u = sp - 56; qi = 15 - (u >> 1); c = u & 1; }
  else { qi = 7 - (sp - 72); c = 0; }
  const int jbeg = c * 8, jend = min(jbeg + 7, qi);
  const int q0 = b * 2048 + qi * 64, myq = w * 16, rowloc = qd * 4;
  const float c1 = 0.04508422f;                 // log2(e)/32

  short8 aQ[2];
#pragma unroll
  for (int ks = 0; ks < 2; ++ks)
    aQ[ks] = *(const short8*)(Qw + (q0 + myq + ln) * 64 + ks * 32 + qd * 8);

  f32x4 O[4];
#pragma unroll
  for (int i = 0; i < 4; ++i) O[i] = (f32x4){0.f,0.f,0.f,0.f};
  float lacc[4] = {0.f, 0.f, 0.f, 0.f};

  {
    const int kb = b * 2048 + jbeg * 64;
#pragma unroll
    for (int i = 0; i < 2; ++i){
      int cgl = t + i * 256, row = cgl >> 3, sub = cgl & 7;
      *(u32x4*)&Kl[0][row][sub * 8] = *(const u32x4*)(Kw + (kb + row) * 64 + sub * 8);
      *(u32x4*)&Vl[0][row][sub * 8] = *(const u32x4*)(Vtw + (b * 64 + row) * 2048 + jbeg * 64 + sub * 8);
    }
  }

  for (int j = jbeg; j <= jend; ++j){
    __syncthreads();
    const int cur = (j - jbeg) & 1, nxt = cur ^ 1;
    u32x4 kreg[2], vreg[2];
    if (j < jend){
      const int kb = b * 2048 + (j + 1) * 64;
#pragma unroll
      for (int i = 0; i < 2; ++i){
        int cgl = t + i * 256, row = cgl >> 3, sub = cgl & 7;
        kreg[i] = *(const u32x4*)(Kw + (kb + row) * 64 + sub * 8);
        vreg[i] = *(const u32x4*)(Vtw + (b * 64 + row) * 2048 + (j + 1) * 64 + sub * 8);
      }
    }
    f32x4 S[4];
#pragma unroll
    for (int nt = 0; nt < 4; ++nt) S[nt] = (f32x4){0.f,0.f,0.f,0.f};
#pragma unroll
    for (int ks = 0; ks < 2; ++ks)
#pragma unroll
      for (int nt = 0; nt < 4; ++nt){
        short8 bK = *(const short8*)&Kl[cur][nt * 16 + ln][ks * 32 + qd * 8];
        S[nt] = __builtin_amdgcn_mfma_f32_16x16x32_bf16(aQ[ks], bK, S[nt], 0, 0, 0);
      }
    const bool dtile = (j == qi);
#pragma unroll
    for (int nt = 0; nt < 4; ++nt){
      const int cl = nt * 16 + ln;
      f32x4 sv = S[nt];
#pragma unroll
      for (int r = 0; r < 4; ++r){
        float p = __builtin_amdgcn_exp2f(sv[r] * c1);
        if (dtile && cl > myq + rowloc + r) p = 0.f;
        lacc[r] += p;
        Pl[w][rowloc + r][cl] = f2bf(p);
      }
    }
#pragma unroll
    for (int ks = 0; ks < 2; ++ks){
      short8 aP = *(const short8*)&Pl[w][ln][ks * 32 + qd * 8];
#pragma unroll
      for (int ht = 0; ht < 4; ++ht){
        short8 bV = *(const short8*)&Vl[cur][ht * 16 + ln][ks * 32 + qd * 8];
        O[ht] = __builtin_amdgcn_mfma_f32_16x16x32_bf16(aP, bV, O[ht], 0, 0, 0);
      }
    }
    if (j < jend){
#pragma unroll
      for (int i = 0; i < 2; ++i){
        int cgl = t + i * 256, row = cgl >> 3, sub = cgl & 7;
        *(u32x4*)&Kl[nxt][row][sub * 8] = kreg[i];
        *(u32x4*)&Vl[nxt][row][sub * 8] = vreg[i];
      }
    }
  }

  float lred[4];
#pragma unroll
  for (int r = 0; r < 4; ++r){
    float v = lacc[r];
    v += __shfl_xor(v, 1);
    v += __shfl_xor(v, 2);
    v += __shfl_xor(v, 4);
    v += __shfl_xor(v, 8);
    lred[r] = v;
  }
  float* Opc = Op + c * 1048576;
  float* lpc = lp + c * 16384;
#pragma unroll
  for (int r = 0; r < 4; ++r){
    const int rowg = q0 + myq + rowloc + r;
#pragma unroll
    for (int ht = 0; ht < 4; ++ht)
      Opc[rowg * 64 + ht * 16 + ln] = O[ht][r];
    if (ln == 0) lpc[rowg] = lred[r];
  }
}

// ---------------- kernel 3: sum valid chunk partials + normalize
__global__ __launch_bounds__(256) void nrm_k(const float* __restrict__ Op,
                                             const float* __restrict__ lp,
                                             float* __restrict__ out){
  const int idx = (blockIdx.x * 256 + threadIdx.x) * 4;
  const int row = idx >> 6;
  const int qi = (row >> 6) & 31;
  const int nch = (qi >> 3) + 1;
  f32x4 s = (f32x4){0.f,0.f,0.f,0.f};
  float lsum = 0.f;
  for (int c = 0; c < nch; ++c){
    f32x4 v = *(const f32x4*)(Op + c * 1048576 + idx);
    s.x += v.x; s.y += v.y; s.z += v.z; s.w += v.w;
    lsum += lp[c * 16384 + row];
  }
  const float inv = 1.0f / lsum;
  s.x *= inv; s.y *= inv; s.z *= inv; s.w *= inv;
  *(f32x4*)(out + idx) = s;
}

extern "C" void kernel_launch(void* const* d_in, const int* in_sizes, int n_in,
                              void* d_out, int out_size, void* d_ws, size_t ws_size,
                              hipStream_t stream){
  const float* X  = (const float*)d_in[0];
  const float* Wk = (const float*)d_in[1];
  const float* Wq = (const float*)d_in[2];
  const float* Wv = (const float*)d_in[3];
  float* out = (float*)d_out;
  char* ws = (char*)d_ws;
  unsigned short* Wb2 = (unsigned short*)(ws);
  unsigned short* Qw  = (unsigned short*)(ws + 393216);
  unsigned short* Kw  = (unsigned short*)(ws + 2490368);
  unsigned short* Vtw = (unsigned short*)(ws + 4587520);
  float* Op = (float*)(ws + 6684672);
  float* lp = (float*)(ws + 23461888);

  hipLaunchKernelGGL(wcvt_k, dim3(96),   dim3(256), 0, stream, Wk, Wq, Wv, Wb2);
  hipLaunchKernelGGL(qkv_k,  dim3(1024), dim3(192), 0, stream, X, Wb2, Qw, Kw, Vtw);
  hipLaunchKernelGGL(attn_k, dim3(640),  dim3(256), 0, stream, Qw, Kw, Vtw, Op, lp);
  hipLaunchKernelGGL(nrm_k,  dim3(1024), dim3(256), 0, stream, Op, lp, out);
}